// Round 8
// baseline (965.268 us; speedup 1.0000x reference)
//
#include <hip/hip_runtime.h>
#include <stdint.h>

#define NROWS  65536
#define KCODES 1024
#define DDIM   256

// ---- ws layout (bytes) ----
// 0       : double lossacc
// 1024    : float counts[1024]
// 8192    : float n2e[1024]
// 16384   : float n2x[65536]            (256KB)
// 278528  : int   idx[65536]            (256KB)
// 589824  : ushort ehi[8][1024][32]     (512KB, K-tiled bf16 hi, k-quarter XOR-swizzled)
// 1114112 : ushort elo[8][1024][32]     (512KB, K-tiled bf16 lo, linear)
// end 1638400

typedef short short8 __attribute__((ext_vector_type(8)));
typedef float f32x4  __attribute__((ext_vector_type(4)));

__device__ __forceinline__ uint32_t rotl32(uint32_t x, uint32_t r){ return (x<<r)|(x>>(32u-r)); }

// JAX threefry2x32, key=(0,42), counter pair (e0, e0+2^25): rows n and n+32768 share one call.
__device__ __forceinline__ void tf2(uint32_t e0, uint32_t& o0, uint32_t& o1){
  const uint32_t ks0 = 0u, ks1 = 42u, ks2 = 0x1BD11BDAu ^ 42u;
  uint32_t x0 = e0, x1 = e0 + 33554432u;
  x0 += ks0; x1 += ks1;
#define TF_R(rr) { x0 += x1; x1 = rotl32(x1, rr); x1 ^= x0; }
  TF_R(13) TF_R(15) TF_R(26) TF_R(6)   x0 += ks1; x1 += ks2 + 1u;
  TF_R(17) TF_R(29) TF_R(16) TF_R(24)  x0 += ks2; x1 += ks0 + 2u;
  TF_R(13) TF_R(15) TF_R(26) TF_R(6)   x0 += ks0; x1 += ks1 + 3u;
  TF_R(17) TF_R(29) TF_R(16) TF_R(24)  x0 += ks1; x1 += ks2 + 4u;
  TF_R(13) TF_R(15) TF_R(26) TF_R(6)   x0 += ks2; x1 += ks0 + 5u;
#undef TF_R
  o0 = x0; o1 = x1;
}

__device__ __forceinline__ float gum(uint32_t bits){
  float f = __uint_as_float((bits >> 9) | 0x3f800000u) - 1.0f;  // [0,1-2^-23]
  float u = fmaxf(1e-9f, f + 1e-9f);
  return -logf(-logf(u));
}

__device__ __forceinline__ unsigned short bf16rne(float x){
  uint32_t u = __float_as_uint(x);
  return (unsigned short)((u + 0x7FFFu + ((u >> 16) & 1u)) >> 16);
}
__device__ __forceinline__ float bf2f(unsigned short h){ return __uint_as_float(((uint32_t)h) << 16); }

__device__ __forceinline__ void gld16(const void* g, void* l){
  __builtin_amdgcn_global_load_lds((const __attribute__((address_space(1))) uint32_t*)g,
                                   (__attribute__((address_space(3))) uint32_t*)l, 16, 0, 0);
}

extern "C" __global__ void __launch_bounds__(1024) k_init(float* counts, double* lossacc){
  int t = threadIdx.x;
  if (t < KCODES) counts[t] = 0.f;
  if (t == 0) *lossacc = 0.0;
}

// emb -> bf16 hi/lo, K-step-tiled. ehi: k-quarter XOR-swizzled (bank-conflict-free b128
// reads while keeping global_load_lds staging a pure linear copy). elo: linear (read
// straight from global into regs, no LDS).
extern "C" __global__ void __launch_bounds__(512) k_split(const float* __restrict__ emb,
    unsigned short* __restrict__ ehi, unsigned short* __restrict__ elo){
  int e = blockIdx.x * 512 + threadIdx.x;   // grid 512 -> 262144
  float v = emb[e];
  unsigned short h = bf16rne(v);
  unsigned short lo2 = bf16rne(v - bf2f(h));
  int c = e >> 8, d = e & 255;
  int q = (d & 31) >> 3, el = d & 7;
  int p = q ^ ((c >> 1) & 3);               // swizzled physical k-quarter
  ehi[(d >> 5) * 32768 + c * 32 + p * 8 + el] = h;
  elo[(d >> 5) * 32768 + c * 32 + (d & 31)]  = lo2;
}

extern "C" __global__ void __launch_bounds__(256) k_n2e(const float* __restrict__ emb,
                                                        float* __restrict__ n2e){
  int w = threadIdx.x >> 6, l = threadIdx.x & 63;
  int c = blockIdx.x * 4 + w;
  double acc = 0.0;
  #pragma unroll
  for (int jj=0; jj<4; jj++){
    float v = emb[c*DDIM + l + 64*jj];
    acc += (double)v * (double)v;
  }
  #pragma unroll
  for (int off=32; off>0; off>>=1) acc += __shfl_down(acc, off);
  if (l == 0) n2e[c] = (float)acc;
}

extern "C" __global__ void __launch_bounds__(256) k_n2x(const float* __restrict__ in,
                                                        float* __restrict__ n2x){
  int n = blockIdx.x * 256 + threadIdx.x;
  int b = n >> 10, hw = n & 1023;
  const float* p = in + (size_t)b * (DDIM*1024) + hw;
  double acc = 0.0;
  for (int d=0; d<DDIM; d++){
    float v = p[(size_t)d*1024];
    acc += (double)v * (double)v;
  }
  n2x[n] = (float)acc;
}

// Fused MFMA GEMM (3-term bf16 split) + gumbel-argmax + entropy.
// Double-buffered B-hi (LDS, swizzled) + A (LDS); b_lo global->reg.
extern "C" __global__ void __launch_bounds__(512, 2) k_main(
    const float* __restrict__ in,
    const unsigned short* __restrict__ ehi, const unsigned short* __restrict__ elo,
    const float* __restrict__ n2x, const float* __restrict__ n2e,
    int* __restrict__ idxb, float* __restrict__ counts, double* __restrict__ lossacc)
{
  __shared__ __align__(16) unsigned short BufH[2][32768];  // 128 KB; [0] reused as sbuf
  __shared__ __align__(16) unsigned short AhiS[2][2560];   // 64 rows x 40 (b128-aligned pad)
  __shared__ __align__(16) unsigned short AloS[2][2560];

  const int t = threadIdx.x;
  const int w = t >> 6, l = t & 63;
  const int row0 = blockIdx.x * 32;
  const int b1 = row0 >> 10;
  const int hw0 = row0 & 1023;
  const int wc = w * 128;
  const int pq = (l >> 4) ^ ((l >> 1) & 3);   // physical k-quarter for swizzled B read

  // n2e for this thread's 8 columns (was LDS; now regs)
  float n2ec[8];
  #pragma unroll
  for (int ct = 0; ct < 8; ct++) n2ec[ct] = n2e[wc + ct*16 + (l & 15)];

  f32x4 acc[4][8];
  #pragma unroll
  for (int rt=0; rt<4; rt++)
    #pragma unroll
    for (int ct=0; ct<8; ct++)
      acc[rt][ct] = (f32x4){0.f,0.f,0.f,0.f};

  const int s2f = (l >= 32);
  const int ab  = b1 + (s2f ? 32 : 0);
  const int ahw = hw0 + l - (s2f ? 32 : 0);

  // ---- prologue: stage ks=0 into buffer 0 ----
  {
    #pragma unroll
    for (int i2 = 0; i2 < 8; i2++){
      int off = (w*8 + i2) * 1024;
      gld16((const char*)ehi + off + l*16, (char*)&BufH[0][0] + off);
    }
    #pragma unroll
    for (int i2 = 0; i2 < 4; i2++){
      int dd = w + 8*i2;
      float v = in[((size_t)(ab*256 + dd))*1024 + ahw];
      unsigned short h = bf16rne(v);
      AhiS[0][l*40 + dd] = h;
      AloS[0][l*40 + dd] = bf16rne(v - bf2f(h));
    }
  }
  __syncthreads();

  for (int ks = 0; ks < 8; ks++){
    const int cur = ks & 1, nxt = cur ^ 1;
    // b_lo (current): global->reg, L2-resident, consumed in group 3
    short8 bl[8];
    #pragma unroll
    for (int ct = 0; ct < 8; ct++)
      bl[ct] = *(const short8*)&elo[(size_t)ks*32768 + (size_t)(wc + ct*16 + (l & 15))*32 + (l >> 4)*8];
    // prefetch next B tile (overlaps with this step's MFMAs; drained at the barrier)
    if (ks < 7){
      const char* gH = (const char*)ehi + (size_t)(ks+1) * 65536;
      #pragma unroll
      for (int i2 = 0; i2 < 8; i2++){
        int off = (w*8 + i2) * 1024;
        gld16(gH + off + l*16, (char*)&BufH[nxt][0] + off);
      }
    }
    // prefetch next A into regs
    float aN[4];
    if (ks < 7){
      #pragma unroll
      for (int i2 = 0; i2 < 4; i2++){
        int dd = w + 8*i2;
        aN[i2] = in[((size_t)(ab*256 + (ks+1)*32 + dd))*1024 + ahw];
      }
    }
    // current fragments
    short8 ah[4], bh[8];
    #pragma unroll
    for (int rt = 0; rt < 4; rt++)
      ah[rt] = *(const short8*)&AhiS[cur][(rt*16 + (l & 15))*40 + (l >> 4)*8];
    #pragma unroll
    for (int ct = 0; ct < 8; ct++)
      bh[ct] = *(const short8*)&BufH[cur][(size_t)(wc + ct*16 + (l & 15))*32 + pq*8];
    // group 1: hi x hi
    #pragma unroll
    for (int ct=0; ct<8; ct++)
      #pragma unroll
      for (int rt=0; rt<4; rt++)
        acc[rt][ct] = __builtin_amdgcn_mfma_f32_16x16x32_bf16(ah[rt], bh[ct], acc[rt][ct], 0, 0, 0);
    // group 2: lo x hi (a_lo loaded per-rt to limit liveness)
    #pragma unroll
    for (int rt=0; rt<4; rt++){
      short8 alr = *(const short8*)&AloS[cur][(rt*16 + (l & 15))*40 + (l >> 4)*8];
      #pragma unroll
      for (int ct=0; ct<8; ct++)
        acc[rt][ct] = __builtin_amdgcn_mfma_f32_16x16x32_bf16(alr, bh[ct], acc[rt][ct], 0, 0, 0);
    }
    // group 3: hi x lo
    #pragma unroll
    for (int ct=0; ct<8; ct++)
      #pragma unroll
      for (int rt=0; rt<4; rt++)
        acc[rt][ct] = __builtin_amdgcn_mfma_f32_16x16x32_bf16(ah[rt], bl[ct], acc[rt][ct], 0, 0, 0);
    // store next A (read next iteration, after the barrier)
    if (ks < 7){
      #pragma unroll
      for (int i2 = 0; i2 < 4; i2++){
        int dd = w + 8*i2;
        unsigned short h = bf16rne(aN[i2]);
        AhiS[nxt][l*40 + dd] = h;
        AloS[nxt][l*40 + dd] = bf16rne(aN[i2] - bf2f(h));
      }
    }
    __syncthreads();
  }

  // ---- epilogue: 4 groups of 8 row-pairs (n, n+32768) ----
  float* sbuf = (float*)&BufH[0][0];   // 16 rows x 1024 f32 = 64KB
  for (int g=0; g<4; g++){
    __syncthreads();
    {
      int fr = l >> 4;
      if ((fr >> 1) == (g & 1)){
        const int rtA = g >> 1, rtB = 2 + (g >> 1);
        const int base = (fr & 1) * 4;
        #pragma unroll
        for (int r=0; r<4; r++){
          float t1 = n2x[row0 + g*8 + base + r];            // broadcast within 16-lane group
          float u2 = n2x[row0 + g*8 + base + r + 32768];
          #pragma unroll
          for (int ct=0; ct<8; ct++){
            int col = wc + ct*16 + (l & 15);
            // s = -d2 = fl(2*dot - fl(n2x+n2e)): 2*dot exact => fmaf == reference rounding
            sbuf[(base+r)*1024 + col]   = fmaf(2.0f, acc[rtA][ct][r], -(t1 + n2ec[ct]));
            sbuf[(8+base+r)*1024 + col] = fmaf(2.0f, acc[rtB][ct][r], -(u2 + n2ec[ct]));
          }
        }
      }
    }
    __syncthreads();
    {
      const int n1 = row0 + g*8 + w;
      const int n2v = n1 + 32768;
      const float* s1 = sbuf + w*1024;
      const float* s2 = sbuf + (8+w)*1024;
      float zb1=-INFINITY, zb2=-INFINITY; int cb1=0, cb2=0;
      float ms1=-INFINITY, ms2=-INFINITY;
      for (int j=0;j<16;j++){
        int c = l + 64*j;
        float sA = s1[c], sB = s2[c];
        uint32_t o0, o1; tf2((uint32_t)n1*1024u + (uint32_t)c, o0, o1);
        float z1 = sA + gum(o0), z2 = sB + gum(o1);
        if (z1 > zb1){ zb1 = z1; cb1 = c; }
        if (z2 > zb2){ zb2 = z2; cb2 = c; }
        ms1 = fmaxf(ms1, sA); ms2 = fmaxf(ms2, sB);
      }
      #pragma unroll
      for (int off=1; off<64; off<<=1){
        float oz = __shfl_xor(zb1, off); int oc = __shfl_xor(cb1, off);
        if (oz > zb1 || (oz == zb1 && oc < cb1)){ zb1 = oz; cb1 = oc; }
        oz = __shfl_xor(zb2, off); oc = __shfl_xor(cb2, off);
        if (oz > zb2 || (oz == zb2 && oc < cb2)){ zb2 = oz; cb2 = oc; }
        ms1 = fmaxf(ms1, __shfl_xor(ms1, off));
        ms2 = fmaxf(ms2, __shfl_xor(ms2, off));
      }
      float E1=0.f, SE1=0.f, E2=0.f, SE2=0.f;
      for (int j=0;j<16;j++){
        int c = l + 64*j;
        float t1 = s1[c] - ms1; float e1 = __expf(t1); E1 += e1; SE1 = fmaf(t1, e1, SE1);
        float t2 = s2[c] - ms2; float e2 = __expf(t2); E2 += e2; SE2 = fmaf(t2, e2, SE2);
      }
      #pragma unroll
      for (int off=1; off<64; off<<=1){
        E1 += __shfl_xor(E1, off); SE1 += __shfl_xor(SE1, off);
        E2 += __shfl_xor(E2, off); SE2 += __shfl_xor(SE2, off);
      }
      float lz1 = logf(E1), lz2 = logf(E2);
      float H1 = SE1/E1 - lz1, H2 = SE2/E2 - lz2;   // clip-correction dropped (<1e-4 on loss)
      if (l == 0){
        idxb[n1] = cb1; idxb[n2v] = cb2;
        atomicAdd(&counts[cb1], 1.0f);
        atomicAdd(&counts[cb2], 1.0f);
        atomicAdd(lossacc, (double)H1 + (double)H2);
      }
    }
  }
}

extern "C" __global__ void __launch_bounds__(1024) k_gather(const float* __restrict__ emb,
                                                            const int* __restrict__ idxb,
                                                            float* __restrict__ out){
  int bd = blockIdx.x;            // b*256 + d
  int hw = threadIdx.x;
  int b = bd >> 8, d = bd & 255;
  int row = idxb[b*1024 + hw];
  out[1 + (size_t)bd*1024 + hw] = emb[(size_t)row*DDIM + d];
}

extern "C" __global__ void __launch_bounds__(1024) k_final(const float* __restrict__ counts,
                                                           const double* __restrict__ lossacc,
                                                           float* __restrict__ out){
  __shared__ float red[16];
  int t = threadIdx.x;
  float avg = counts[t] * (1.0f/65536.0f);
  float term = avg * logf(avg + 1e-10f);
  #pragma unroll
  for (int off=1; off<64; off<<=1) term += __shfl_xor(term, off);
  if ((t & 63) == 0) red[t >> 6] = term;
  __syncthreads();
  if (t == 0){
    float s = 0.f;
    #pragma unroll
    for (int i=0;i<16;i++) s += red[i];
    out[16777217] = expf(-s);
    double m = *lossacc / 65536.0;
    out[0] = (float)(0.25 * m);
  }
}

extern "C" void kernel_launch(void* const* d_in, const int* in_sizes, int n_in,
                              void* d_out, int out_size, void* d_ws, size_t ws_size,
                              hipStream_t stream){
  const float* in  = (const float*)d_in[0];   // [64,256,32,32]
  const float* emb = (const float*)d_in[1];   // [1024,256]
  float* out = (float*)d_out;
  char* ws = (char*)d_ws;
  double* lossacc = (double*)(ws + 0);
  float*  counts  = (float*) (ws + 1024);
  float*  n2e     = (float*) (ws + 8192);
  float*  n2x     = (float*) (ws + 16384);
  int*    idxb    = (int*)   (ws + 278528);
  unsigned short* ehi = (unsigned short*)(ws + 589824);
  unsigned short* elo = (unsigned short*)(ws + 1114112);

  k_init  <<<dim3(1),     dim3(1024), 0, stream>>>(counts, lossacc);
  k_split <<<dim3(512),   dim3(512),  0, stream>>>(emb, ehi, elo);
  k_n2e   <<<dim3(256),   dim3(256),  0, stream>>>(emb, n2e);
  k_n2x   <<<dim3(256),   dim3(256),  0, stream>>>(in, n2x);
  k_main  <<<dim3(1024),  dim3(512),  0, stream>>>(in, ehi, elo, n2x, n2e, idxb, counts, lossacc);
  k_gather<<<dim3(16384), dim3(1024), 0, stream>>>(emb, idxb, out);
  k_final <<<dim3(1),     dim3(1024), 0, stream>>>(counts, lossacc, out);
}